// Round 1
// 5477.500 us; speedup vs baseline: 1.3526x; 1.3526x over previous
//
#include <hip/hip_runtime.h>
#include <cstdint>
#include <cstddef>

// LSTM B=64,T=1024,I=256,H=512. Persistent kernel, 64 WGs = 4 bg x 16 hg.
// WG (bg,hg): batches bg*16..+15, hidden hg*32..+31 -> 128 gate rows, K=768.
// Weights held in VGPRs: per lane 2 tiles x 24 x short8x (192 VGPRs).
// Tile row mapping is hidden-major: A row r = (gate r&3, hidden r>>2), so the
// 16x16x32 C/D layout (col=lane&15, row=(lane>>4)*4+reg) puts all 4 gates of
// one (hidden,batch) into one lane's 4 acc regs -> lane-local activation.
// Full K=768 per wave per tile => no partial-sum LDS buffer, no 2nd barrier.
// h exchange: TAGGED words ((t)<<16 | bf16(h)), double-buffered [2][64][512],
// relaxed agent-scope 4B atomics; consumers poll data words directly (tag==t).
// Overwrite safety: producer writes tag t+3 over t+1 only after consuming all
// of tag t+2, which transitively (via the per-step __syncthreads) requires
// every group WG to have finished reading tag t+1. ws poison 0xAAAA never
// matches a tag (tags 1..1024) -> no memset needed.
// a_s is double-buffered -> exactly ONE barrier per step.
// out[:, t-1, :]: each WG writes batch (hg+t)&15 (2 KB, nontemporal) -> the
// write load is uniform, no rotating straggler WG on the critical path.

#define NBATCH 64
#define TSTEPS 1024
#define IDIM   256
#define HDIM   512
#define KDIM   768
#define WS     776          // ushort k-stride (odd # of 16B slots -> spread banks)
#define ABUF_USHORT (16 * WS)            // 12416 ushorts = 24832 B per buffer
#define SMEM_BYTES  (2 * ABUF_USHORT * 2)  // 49664 B

#define HB_WORDS 32768      // words per h buffer: 64*512

typedef __attribute__((ext_vector_type(8))) short short8x;   // 8 bf16
typedef __attribute__((ext_vector_type(4))) float f32x4;

__device__ __forceinline__ float sigmoid_f(float v) {
    return 1.0f / (1.0f + __expf(-v));
}
__device__ __forceinline__ float tanh_f(float v) {
    float a = fabsf(v);
    float e = __expf(-2.0f * a);
    float r = (1.0f - e) / (1.0f + e);
    return v >= 0.0f ? r : -r;
}
__device__ __forceinline__ unsigned short f2bf(float f) {
    unsigned int u = __float_as_uint(f);
    return (unsigned short)((u + 0x7fffu + ((u >> 16) & 1u)) >> 16);  // RNE
}
__device__ __forceinline__ unsigned long long pack4(float4 v) {
    unsigned long long b0 = f2bf(v.x), b1 = f2bf(v.y), b2 = f2bf(v.z), b3 = f2bf(v.w);
    return b0 | (b1 << 16) | (b2 << 32) | (b3 << 48);
}

__global__ void __launch_bounds__(256, 1) lstm_persistent(
    const float* __restrict__ x,      // [64][1024][256]
    const float* __restrict__ w_ih,   // [2048][256]
    const float* __restrict__ w_hh,   // [2048][512]
    const float* __restrict__ b_ih,   // [2048]
    const float* __restrict__ b_hh,   // [2048]
    float* __restrict__ out,          // [64][1024][512] + h_n + c_n
    unsigned int* __restrict__ h_tb)  // tagged h: [2][64][512] uint32 in ws
{
    const int tid = threadIdx.x;
    const int wg  = blockIdx.x;
    const int bg  = wg >> 4;     // 0..3
    const int hg  = wg & 15;     // 0..15

    extern __shared__ char smem[];
    unsigned short* a0 = (unsigned short*)smem;
    unsigned short* a1 = a0 + ABUF_USHORT;

    const int wv   = tid >> 6;          // wave 0..3
    const int lane = tid & 63;
    const int ln   = lane & 15;         // A-row supplied / batch col of D
    const int q    = lane >> 4;         // quad: k-slice of A/B, hidden of D

    // ---- one-time: weights -> VGPRs. Wave wv owns tiles {2wv, 2wv+1}. ----
    // A row r of tile T: global gate row = (r&3)*512 + hg*32 + T*4 + (r>>2).
    // Lane (q,ln) supplies row ln, k = s*32 + q*8 .. +8 for MFMA step s.
    short8x af0[24], af1[24];
    float bias0[4], bias1[4];
    #pragma unroll
    for (int tau = 0; tau < 2; ++tau) {
        const int T  = wv * 2 + tau;
        const int gr = (ln & 3) * HDIM + hg * 32 + T * 4 + (ln >> 2);
        #pragma unroll
        for (int s = 0; s < 24; ++s) {
            // s<8 -> whole 8-chunk inside w_ih (k<256); s>=8 -> w_hh
            const float* src = (s < 8)
                ? (w_ih + (size_t)gr * IDIM + (s * 32 + q * 8))
                : (w_hh + (size_t)gr * HDIM + ((s - 8) * 32 + q * 8));
            float4 v0 = *(const float4*)(src);
            float4 v1 = *(const float4*)(src + 4);
            union { short8x v; unsigned long long u[2]; } tmp;
            tmp.u[0] = pack4(v0);
            tmp.u[1] = pack4(v1);
            if (tau == 0) af0[s] = tmp.v; else af1[s] = tmp.v;
        }
        // output of this lane for tile T: hidden = hg*32 + T*4 + q
        const int hid = hg * 32 + T * 4 + q;
        #pragma unroll
        for (int j = 0; j < 4; ++j) {
            float bv = b_ih[j * HDIM + hid] + b_hh[j * HDIM + hid];
            if (tau == 0) bias0[j] = bv; else bias1[j] = bv;
        }
    }

    // ---- per-thread mappings ----
    // staging / consume: thread -> (batch sn, chunk sj)
    const int sn  = tid >> 4;           // 0..15 (local batch)
    const int sj  = tid & 15;           // 0..15
    const int gbn = bg * 16 + sn;       // global batch for staging role
    const float* xbase = x + (size_t)gbn * TSTEPS * IDIM + sj * 16;

    // producer: lane (wv,q,ln) -> batch bg*16+ln, hiddens hg*32+wv*8+q (+4)
    const size_t hb_lane = (size_t)(bg * 16 + ln) * HDIM + hg * 32 + wv * 8 + q;
    float c0 = 0.0f, c1 = 0.0f, h0f = 0.0f, h1f = 0.0f;

    const unsigned long long tagmask = 0xffff0000ffff0000ull;

    for (int t = 0; t < TSTEPS; ++t) {
        unsigned short* abuf = (t & 1) ? a1 : a0;
        unsigned short* axp  = abuf + sn * WS + sj * 16;          // x region
        unsigned short* ahp  = abuf + sn * WS + IDIM + sj * 32;   // h region

        // ---- stage x_t (fp32 -> bf16) ----
        {
            const float* xp = xbase + (size_t)t * IDIM;
            float4 v0 = *(const float4*)(xp);
            float4 v1 = *(const float4*)(xp + 4);
            float4 v2 = *(const float4*)(xp + 8);
            float4 v3 = *(const float4*)(xp + 12);
            *(unsigned long long*)(axp + 0)  = pack4(v0);
            *(unsigned long long*)(axp + 4)  = pack4(v1);
            *(unsigned long long*)(axp + 8)  = pack4(v2);
            *(unsigned long long*)(axp + 12) = pack4(v3);
        }

        // ---- poll tagged h_t directly (tag == t), payload arrives with it ----
        if (t > 0) {
            const unsigned long long* hp = (const unsigned long long*)
                (h_tb + (size_t)(t & 1) * HB_WORDS + (size_t)gbn * HDIM + sj * 32);
            unsigned long long hv[16];
            const unsigned long long tagpat =
                ((unsigned long long)(unsigned)t << 48) |
                ((unsigned long long)(unsigned)t << 16);
            unsigned pend = 0xffffu;
            while (pend) {
                unsigned np = 0;
                #pragma unroll
                for (int u = 0; u < 16; ++u) {
                    if (pend & (1u << u)) {
                        hv[u] = __hip_atomic_load(hp + u, __ATOMIC_RELAXED,
                                                  __HIP_MEMORY_SCOPE_AGENT);
                    }
                }
                #pragma unroll
                for (int u = 0; u < 16; ++u) {
                    if ((pend & (1u << u)) && (hv[u] & tagmask) != tagpat)
                        np |= (1u << u);
                }
                pend = np;
            }
            // payload: low 16 bits of each 4B word -> packed bf16 pairs
            unsigned int pk[16];
            #pragma unroll
            for (int u = 0; u < 16; ++u) {
                pk[u] = (unsigned int)(hv[u] & 0xffffu)
                      | ((unsigned int)((hv[u] >> 32) & 0xffffu) << 16);
            }
            unsigned int* ahp32 = (unsigned int*)ahp;
            #pragma unroll
            for (int v = 0; v < 4; ++v) {
                uint4 w4 = make_uint4(pk[4*v], pk[4*v+1], pk[4*v+2], pk[4*v+3]);
                *(uint4*)(ahp32 + 4*v) = w4;
            }
            // spread writer: WG hg writes batch (hg+t)&15 of out[:, t-1, :]
            if (sn == ((hg + t) & 15)) {
                float* op = out + ((size_t)gbn * TSTEPS + (t - 1)) * HDIM + sj * 32;
                #pragma unroll
                for (int v = 0; v < 8; ++v) {
                    unsigned int w0 = pk[2*v], w1 = pk[2*v+1];
                    f32x4 f4;
                    f4[0] = __uint_as_float(w0 << 16);
                    f4[1] = __uint_as_float(w0 & 0xffff0000u);
                    f4[2] = __uint_as_float(w1 << 16);
                    f4[3] = __uint_as_float(w1 & 0xffff0000u);
                    __builtin_nontemporal_store(f4, (f32x4*)(op + 4*v));
                }
            }
        } else {
            unsigned int* ahp32 = (unsigned int*)ahp;
            uint4 z = make_uint4(0u, 0u, 0u, 0u);
            #pragma unroll
            for (int v = 0; v < 4; ++v) *(uint4*)(ahp32 + 4*v) = z;
        }
        __syncthreads();   // the ONLY barrier per step: a_s[t&1] staged

        // ---- MFMA: [128 x 768] x [768 x 16], wave = 2 tiles, full K ----
        const unsigned short* Bbase = abuf + (size_t)ln * WS + q * 8;
        f32x4 acc0 = {0.f, 0.f, 0.f, 0.f};
        f32x4 acc1 = {0.f, 0.f, 0.f, 0.f};
        #pragma unroll
        for (int s = 0; s < 24; ++s) {
            short8x bf = *(const short8x*)(Bbase + s * 32);
            acc0 = __builtin_amdgcn_mfma_f32_16x16x32_bf16(af0[s], bf, acc0, 0, 0, 0);
            acc1 = __builtin_amdgcn_mfma_f32_16x16x32_bf16(af1[s], bf, acc1, 0, 0, 0);
        }

        // ---- lane-local activation + tagged publish (no barrier after) ----
        // acc reg j = gate j (i,f,g,o), hidden q of the tile, batch ln.
        const unsigned int tagw = (unsigned int)(t + 1) << 16;
        unsigned int* hb = h_tb + (size_t)((t + 1) & 1) * HB_WORDS + hb_lane;
        {
            float ig = sigmoid_f(acc0[0] + bias0[0]);
            float fg = sigmoid_f(acc0[1] + bias0[1]);
            float gt = tanh_f   (acc0[2] + bias0[2]);
            float og = sigmoid_f(acc0[3] + bias0[3]);
            c0  = fg * c0 + ig * gt;
            h0f = og * tanh_f(c0);
            __hip_atomic_store(hb, tagw | (unsigned int)f2bf(h0f),
                               __ATOMIC_RELAXED, __HIP_MEMORY_SCOPE_AGENT);
        }
        {
            float ig = sigmoid_f(acc1[0] + bias1[0]);
            float fg = sigmoid_f(acc1[1] + bias1[1]);
            float gt = tanh_f   (acc1[2] + bias1[2]);
            float og = sigmoid_f(acc1[3] + bias1[3]);
            c1  = fg * c1 + ig * gt;
            h1f = og * tanh_f(c1);
            __hip_atomic_store(hb + 4, tagw | (unsigned int)f2bf(h1f),
                               __ATOMIC_RELAXED, __HIP_MEMORY_SCOPE_AGENT);
        }
        // no trailing barrier: next-iter staging targets the OTHER a_s buffer,
        // and passing the next barrier implies all waves left this MFMA phase.
    }

    // ---- final row out[:,1023,:] + h_n, c_n (lanes hold h_T, c_T) ----
    {
        const size_t HN_OFF = (size_t)NBATCH * TSTEPS * HDIM;   // 33554432
        const size_t CN_OFF = HN_OFF + (size_t)NBATCH * HDIM;   // +32768
        const int gb   = bg * 16 + ln;
        const int hid0 = hg * 32 + wv * 8 + q;
        out[((size_t)gb * TSTEPS + (TSTEPS - 1)) * HDIM + hid0]     = h0f;
        out[((size_t)gb * TSTEPS + (TSTEPS - 1)) * HDIM + hid0 + 4] = h1f;
        out[HN_OFF + (size_t)gb * HDIM + hid0]     = h0f;
        out[HN_OFF + (size_t)gb * HDIM + hid0 + 4] = h1f;
        out[CN_OFF + (size_t)gb * HDIM + hid0]     = c0;
        out[CN_OFF + (size_t)gb * HDIM + hid0 + 4] = c1;
    }
}

extern "C" void kernel_launch(void* const* d_in, const int* in_sizes, int n_in,
                              void* d_out, int out_size, void* d_ws, size_t ws_size,
                              hipStream_t stream) {
    const float* x    = (const float*)d_in[0];
    const float* w_ih = (const float*)d_in[1];
    const float* w_hh = (const float*)d_in[2];
    const float* b_ih = (const float*)d_in[3];
    const float* b_hh = (const float*)d_in[4];
    float* out = (float*)d_out;

    // ws: [0, 256KB) tagged h double-buffer. No zeroing needed: 0xAAAA poison
    // can never equal a live tag (tags are 1..1024).
    unsigned int* h_tb = (unsigned int*)d_ws;

    (void)hipFuncSetAttribute((const void*)lstm_persistent,
                        hipFuncAttributeMaxDynamicSharedMemorySize, SMEM_BYTES);

    void* args[] = {(void*)&x, (void*)&w_ih, (void*)&w_hh, (void*)&b_ih,
                    (void*)&b_hh, (void*)&out, (void*)&h_tb};
    hipError_t err = hipLaunchCooperativeKernel((void*)lstm_persistent,
                                                dim3(64), dim3(256), args,
                                                SMEM_BYTES, stream);
    if (err != hipSuccess) {
        hipLaunchKernelGGL(lstm_persistent, dim3(64), dim3(256), SMEM_BYTES,
                           stream, x, w_ih, w_hh, b_ih, b_hh, out, h_tb);
    }
}

// Round 2
// 5356.700 us; speedup vs baseline: 1.3832x; 1.0226x over previous
//
#include <hip/hip_runtime.h>
#include <cstdint>
#include <cstddef>

// LSTM B=64,T=1024,I=256,H=512. Persistent kernel, 32 WGs = 4 bg x 8 hg.
// WG (bg,hg): batches bg*16..+15, hidden hg*64..+63 -> 256 gate rows, K=768.
// Weights in VGPRs: per lane 4 tiles x 24 x short8x (384 VGPRs). Tile tau of
// wave wv covers hiddens hg*64 + wv*16 + hsub*4 + tau (hsub = row>>2), so the
// 16x16x32 C/D layout (col=lane&15, row=(lane>>4)*4+reg) gives reg j = gate j
// and each lane 4 CONSECUTIVE hiddens (tau=0..3) -> activation lane-local AND
// the 4 tagged h words publish as ONE global_store_dwordx4 sc0 sc1.
// h exchange: TAGGED words ((t)<<16 | bf16(h)), double-buffered [2][64][512].
// Consumers poll with 16B global_load_dwordx4 sc0 sc1 (agent-coherent, per-
// dword atomic) -- 8 requests/thread/sweep instead of 16x8B atomics, and only
// 8 consumer WGs per word instead of 16 -> ~4x fewer LLC transactions/step.
// Overwrite safety: producer writes tag t+1 over tag t-1 only after consuming
// all of tag t, which transitively (via each WG's per-step __syncthreads)
// requires every group WG to have finished reading tag t-1. ws poison 0xAAAA
// never matches a tag (tags 1..1024) -> no memset needed.
// a_s double-buffered -> exactly ONE barrier per step. Bias lives in LDS
// (broadcast reads) to keep VGPR peak under the 512/lane budget.

#define NBATCH 64
#define TSTEPS 1024
#define IDIM   256
#define HDIM   512
#define KDIM   768
#define WS     776          // ushort k-stride (odd # of 16B slots -> spread banks)
#define ABUF_USHORT (16 * WS)              // 12416 ushorts = 24832 B per buffer
#define BIAS_OFF    (2 * ABUF_USHORT * 2)  // 49664
#define SMEM_BYTES  (BIAS_OFF + 1024)      // + 256 floats bias = 50688 B

#define HB_WORDS 32768      // words per h buffer: 64*512

typedef __attribute__((ext_vector_type(8))) short short8x;        // 8 bf16
typedef __attribute__((ext_vector_type(4))) float f32x4;
typedef __attribute__((ext_vector_type(4))) unsigned int u32x4;

__device__ __forceinline__ float sigmoid_f(float v) {
    return 1.0f / (1.0f + __expf(-v));
}
__device__ __forceinline__ float tanh_f(float v) {
    float a = fabsf(v);
    float e = __expf(-2.0f * a);
    float r = (1.0f - e) / (1.0f + e);
    return v >= 0.0f ? r : -r;
}
__device__ __forceinline__ unsigned short f2bf(float f) {
    unsigned int u = __float_as_uint(f);
    return (unsigned short)((u + 0x7fffu + ((u >> 16) & 1u)) >> 16);  // RNE
}
__device__ __forceinline__ unsigned long long pack4(float4 v) {
    unsigned long long b0 = f2bf(v.x), b1 = f2bf(v.y), b2 = f2bf(v.z), b3 = f2bf(v.w);
    return b0 | (b1 << 16) | (b2 << 32) | (b3 << 48);
}
__device__ __forceinline__ unsigned int pklo(unsigned int a, unsigned int b) {
    return (a & 0xffffu) | (b << 16);     // two bf16 payloads -> one u32
}

__global__ void __launch_bounds__(256, 1) lstm_persistent(
    const float* __restrict__ x,      // [64][1024][256]
    const float* __restrict__ w_ih,   // [2048][256]
    const float* __restrict__ w_hh,   // [2048][512]
    const float* __restrict__ b_ih,   // [2048]
    const float* __restrict__ b_hh,   // [2048]
    float* __restrict__ out,          // [64][1024][512] + h_n + c_n
    unsigned int* __restrict__ h_tb)  // tagged h: [2][64][512] uint32 in ws
{
    const int tid = threadIdx.x;
    const int wg  = blockIdx.x;
    const int bg  = wg >> 3;     // 0..3
    const int hg  = wg & 7;      // 0..7

    extern __shared__ char smem[];
    unsigned short* a0 = (unsigned short*)smem;
    unsigned short* a1 = a0 + ABUF_USHORT;
    float* bias_s = (float*)(smem + BIAS_OFF);

    const int wv   = tid >> 6;          // wave 0..3
    const int lane = tid & 63;
    const int ln   = lane & 15;         // A-row supplied / batch col of D
    const int q    = lane >> 4;         // quad: k-slice of A/B, hsub of D

    // ---- one-time: weights -> VGPRs (4 tiles per wave) ----
    // A row r=ln of tile tau: gate g=ln&3, hsub=ln>>2;
    // global gate row = g*512 + hg*64 + wv*16 + hsub*4 + tau.
    // Lane (q,ln) supplies row ln, k = s*32 + q*8 .. +8 for MFMA step s.
    short8x af0[24], af1[24], af2[24], af3[24];
    {
        const int grb = (ln & 3) * HDIM + hg * 64 + wv * 16 + (ln >> 2) * 4;
#define LOADW(AF, TAU)                                                        \
        {                                                                     \
            const int gr = grb + (TAU);                                       \
            _Pragma("unroll")                                                 \
            for (int s = 0; s < 24; ++s) {                                    \
                const float* src = (s < 8)                                    \
                    ? (w_ih + (size_t)gr * IDIM + (s * 32 + q * 8))           \
                    : (w_hh + (size_t)gr * HDIM + ((s - 8) * 32 + q * 8));    \
                float4 v0 = *(const float4*)(src);                            \
                float4 v1 = *(const float4*)(src + 4);                        \
                union { short8x v; unsigned long long u[2]; } tmp;            \
                tmp.u[0] = pack4(v0);                                         \
                tmp.u[1] = pack4(v1);                                         \
                AF[s] = tmp.v;                                                \
            }                                                                 \
        }
        LOADW(af0, 0) LOADW(af1, 1) LOADW(af2, 2) LOADW(af3, 3)
#undef LOADW
    }

    // ---- bias -> LDS. Lane-set ln<4 covers tau=ln for its (wv,q). ----
    if (ln < 4) {
        const int tau = ln;
        const int hid = hg * 64 + wv * 16 + q * 4 + tau;
        #pragma unroll
        for (int j = 0; j < 4; ++j)
            bias_s[(wv * 4 + q) * 16 + tau * 4 + j] =
                b_ih[j * HDIM + hid] + b_hh[j * HDIM + hid];
    }

    // ---- per-thread mappings ----
    const int sn  = tid >> 4;           // 0..15 (local batch, staging role)
    const int sj  = tid & 15;           // 0..15
    const int gbn = bg * 16 + sn;       // global batch for staging role
    const float* xbase = x + (size_t)gbn * TSTEPS * IDIM + sj * 16;

    // producer: lane (wv,q,ln) -> batch bg*16+ln, hiddens hg*64+wv*16+q*4 +0..3
    const size_t hb_off = (size_t)(bg * 16 + ln) * HDIM + hg * 64 + wv * 16 + q * 4;
    float c0 = 0.f, c1 = 0.f, c2 = 0.f, c3 = 0.f;
    float hf0 = 0.f, hf1 = 0.f, hf2 = 0.f, hf3 = 0.f;

    for (int t = 0; t < TSTEPS; ++t) {
        unsigned short* abuf = (t & 1) ? a1 : a0;
        unsigned short* axp  = abuf + sn * WS + sj * 16;          // x region
        unsigned int*   ahp32 = (unsigned int*)(abuf + sn * WS + IDIM + sj * 32);

        // ---- stage x_t (fp32 -> bf16) ----
        {
            const float* xp = xbase + (size_t)t * IDIM;
            float4 v0 = *(const float4*)(xp);
            float4 v1 = *(const float4*)(xp + 4);
            float4 v2 = *(const float4*)(xp + 8);
            float4 v3 = *(const float4*)(xp + 12);
            *(unsigned long long*)(axp + 0)  = pack4(v0);
            *(unsigned long long*)(axp + 4)  = pack4(v1);
            *(unsigned long long*)(axp + 8)  = pack4(v2);
            *(unsigned long long*)(axp + 12) = pack4(v3);
        }

        // ---- poll tagged h_t (tag == t) with 16B agent-coherent loads ----
        if (t > 0) {
            const unsigned int* hp =
                h_tb + (size_t)(t & 1) * HB_WORDS + (size_t)gbn * HDIM + sj * 32;
            u32x4 hv[8];
            const unsigned int tagw = (unsigned int)t << 16;
            unsigned pend = 0xffu;
            while (pend) {
                #pragma unroll
                for (int u = 0; u < 8; ++u) {
                    if (pend & (1u << u)) {
                        asm volatile("global_load_dwordx4 %0, %1, off sc0 sc1"
                                     : "=v"(hv[u]) : "v"(hp + u * 4) : "memory");
                    }
                }
                asm volatile("s_waitcnt vmcnt(0)" ::: "memory");
                __builtin_amdgcn_sched_barrier(0);
                unsigned np = 0;
                #pragma unroll
                for (int u = 0; u < 8; ++u) {
                    if (pend & (1u << u)) {
                        unsigned m = ((hv[u][0] ^ tagw) | (hv[u][1] ^ tagw) |
                                      (hv[u][2] ^ tagw) | (hv[u][3] ^ tagw))
                                     & 0xffff0000u;
                        if (m) np |= (1u << u);
                    }
                }
                pend = np;
            }
            // payload -> LDS h region (packed bf16 pairs)
            #pragma unroll
            for (int v = 0; v < 4; ++v) {
                u32x4 a = hv[2 * v], b = hv[2 * v + 1];
                u32x4 w4;
                w4[0] = pklo(a[0], a[1]);
                w4[1] = pklo(a[2], a[3]);
                w4[2] = pklo(b[0], b[1]);
                w4[3] = pklo(b[2], b[3]);
                *(u32x4*)(ahp32 + 4 * v) = w4;
            }
            // spread writer: per bg, WG hg writes batches sn, sn+8 with
            // (sn&7)==((hg+t)&7) of out[:, t-1, :] (full lines, nontemporal)
            if ((sn & 7) == ((hg + t) & 7)) {
                float* op = out + ((size_t)gbn * TSTEPS + (t - 1)) * HDIM + sj * 32;
                #pragma unroll
                for (int u = 0; u < 8; ++u) {
                    u32x4 h4 = hv[u];
                    f32x4 f4;
                    f4[0] = __uint_as_float(h4[0] << 16);
                    f4[1] = __uint_as_float(h4[1] << 16);
                    f4[2] = __uint_as_float(h4[2] << 16);
                    f4[3] = __uint_as_float(h4[3] << 16);
                    __builtin_nontemporal_store(f4, (f32x4*)(op + 4 * u));
                }
            }
        } else {
            u32x4 z = {0u, 0u, 0u, 0u};
            #pragma unroll
            for (int v = 0; v < 4; ++v) *(u32x4*)(ahp32 + 4 * v) = z;
        }
        __syncthreads();   // the ONLY barrier per step: a_s[t&1] staged

        // ---- MFMA: [256 x 768] x [768 x 16], wave = 4 tiles, full K ----
        const unsigned short* Bbase = abuf + (size_t)ln * WS + q * 8;
        f32x4 ac0 = {0.f, 0.f, 0.f, 0.f};
        f32x4 ac1 = {0.f, 0.f, 0.f, 0.f};
        f32x4 ac2 = {0.f, 0.f, 0.f, 0.f};
        f32x4 ac3 = {0.f, 0.f, 0.f, 0.f};
        #pragma unroll
        for (int s = 0; s < 24; ++s) {
            short8x bf = *(const short8x*)(Bbase + s * 32);
            ac0 = __builtin_amdgcn_mfma_f32_16x16x32_bf16(af0[s], bf, ac0, 0, 0, 0);
            ac1 = __builtin_amdgcn_mfma_f32_16x16x32_bf16(af1[s], bf, ac1, 0, 0, 0);
            ac2 = __builtin_amdgcn_mfma_f32_16x16x32_bf16(af2[s], bf, ac2, 0, 0, 0);
            ac3 = __builtin_amdgcn_mfma_f32_16x16x32_bf16(af3[s], bf, ac3, 0, 0, 0);
        }

        // ---- lane-local activation (reg j = gate j) + packed publish ----
        const unsigned int tagw1 = (unsigned int)(t + 1) << 16;
        const float* bsl = bias_s + (wv * 4 + q) * 16;
        u32x4 pub;
#define ACT(ACC, TAU, CREF, HREF)                                             \
        {                                                                     \
            f32x4 bs = *(const f32x4*)(bsl + (TAU) * 4);                      \
            float ig = sigmoid_f(ACC[0] + bs[0]);                             \
            float fg = sigmoid_f(ACC[1] + bs[1]);                             \
            float gt = tanh_f   (ACC[2] + bs[2]);                             \
            float og = sigmoid_f(ACC[3] + bs[3]);                             \
            CREF = fg * CREF + ig * gt;                                       \
            HREF = og * tanh_f(CREF);                                         \
            pub[TAU] = tagw1 | (unsigned int)f2bf(HREF);                      \
        }
        ACT(ac0, 0, c0, hf0)
        ACT(ac1, 1, c1, hf1)
        ACT(ac2, 2, c2, hf2)
        ACT(ac3, 3, c3, hf3)
#undef ACT
        {
            unsigned int* hb = h_tb + (size_t)((t + 1) & 1) * HB_WORDS + hb_off;
            asm volatile("global_store_dwordx4 %0, %1, off sc0 sc1"
                         :: "v"(hb), "v"(pub) : "memory");
        }
        // no trailing barrier: next-iter staging targets the OTHER a_s buffer,
        // and passing the next barrier implies all waves left this MFMA phase.
    }

    // ---- final row out[:,1023,:] + h_n, c_n (lanes hold h_T, c_T) ----
    {
        const size_t HN_OFF = (size_t)NBATCH * TSTEPS * HDIM;   // 33554432
        const size_t CN_OFF = HN_OFF + (size_t)NBATCH * HDIM;   // +32768
        const int gb   = bg * 16 + ln;
        const int hid0 = hg * 64 + wv * 16 + q * 4;
        f32x4 hv4 = {hf0, hf1, hf2, hf3};
        f32x4 cv4 = {c0, c1, c2, c3};
        *(f32x4*)(out + ((size_t)gb * TSTEPS + (TSTEPS - 1)) * HDIM + hid0) = hv4;
        *(f32x4*)(out + HN_OFF + (size_t)gb * HDIM + hid0) = hv4;
        *(f32x4*)(out + CN_OFF + (size_t)gb * HDIM + hid0) = cv4;
    }
}

extern "C" void kernel_launch(void* const* d_in, const int* in_sizes, int n_in,
                              void* d_out, int out_size, void* d_ws, size_t ws_size,
                              hipStream_t stream) {
    const float* x    = (const float*)d_in[0];
    const float* w_ih = (const float*)d_in[1];
    const float* w_hh = (const float*)d_in[2];
    const float* b_ih = (const float*)d_in[3];
    const float* b_hh = (const float*)d_in[4];
    float* out = (float*)d_out;

    // ws: [0, 256KB) tagged h double-buffer. No zeroing needed: 0xAAAA poison
    // can never equal a live tag (tags are 1..1024).
    unsigned int* h_tb = (unsigned int*)d_ws;

    (void)hipFuncSetAttribute((const void*)lstm_persistent,
                        hipFuncAttributeMaxDynamicSharedMemorySize, SMEM_BYTES);

    void* args[] = {(void*)&x, (void*)&w_ih, (void*)&w_hh, (void*)&b_ih,
                    (void*)&b_hh, (void*)&out, (void*)&h_tb};
    hipError_t err = hipLaunchCooperativeKernel((void*)lstm_persistent,
                                                dim3(32), dim3(256), args,
                                                SMEM_BYTES, stream);
    if (err != hipSuccess) {
        hipLaunchKernelGGL(lstm_persistent, dim3(32), dim3(256), SMEM_BYTES,
                           stream, x, w_ih, w_hh, b_ih, b_hh, out, h_tb);
    }
}

// Round 4
// 5141.871 us; speedup vs baseline: 1.4409x; 1.0418x over previous
//
#include <hip/hip_runtime.h>
#include <cstdint>
#include <cstddef>

// LSTM B=64,T=1024,I=256,H=512. Persistent kernel, 32 WGs = 4 bg x 8 hg.
// WG (bg,hg): batches bg*16..+15, hidden hg*64..+63 -> 256 gate rows, K=768.
// Weights in VGPR/AGPR: per lane 4 tiles x 24 x short8x (384 regs). Tile tau
// of wave wv covers hiddens hg*64 + wv*16 + hsub*4 + tau, so the 16x16x32 C/D
// layout (col=lane&15, row=(lane>>4)*4+reg) gives reg j = gate j and each
// lane 4 CONSECUTIVE hiddens -> lane-local activation, ONE dwordx4 publish.
// h exchange: TAGGED words ((t)<<16 | bf16(h)), double-buffered [2][64][512].
// Consumers poll with 16B global_load_dwordx4 sc0 sc1 (system-scope, per-
// dword atomic). Overwrite safety: producer writes tag t+1 over tag t-1 only
// after consuming all of tag t, which transitively (via each WG's per-step
// __syncthreads) requires every group WG to have finished reading tag t-1.
// ws poison 0xAAAA never matches a tag (tags 1..1024) -> no memset needed.
//
// ROUND-3 POST-MORTEM: sc0-only "XCD-local" exchange hung the GPU. The sc
// bits form a 2-bit SCOPE field (sc1:sc0 ~ {CU, SE, device, system}); sc0
// alone = SE scope, insufficient for an 8-CU group spanning SEs -> stale
// polls forever. There is no XCD-L2 scope. Reverted to proven sc0 sc1.
//
// ROUND-4 LEVERS (clock-floor theory: ~600 MHz effective -> VALU instr count
// dominates): (1) rcp/exp2 activations (no IEEE div), (2) v_cvt_pk_bf16_f32
// packing, (3) x loads issued before the poll (latency hides under the
// producer wait; rule-18 sched_barrier before register use), (4) out-store
// moved after publish, re-read from LDS (ack drains in next step's poll,
// not in the pre-barrier vmcnt(0)).

#define NBATCH 64
#define TSTEPS 1024
#define IDIM   256
#define HDIM   512
#define WS     776          // ushort k-stride (odd # of 16B slots -> spread banks)
#define ABUF_USHORT (16 * WS)              // 12416 ushorts = 24832 B per buffer
#define BIAS_OFF    (2 * ABUF_USHORT * 2)  // 49664
#define SMEM_BYTES  (BIAS_OFF + 1024)      // + 256 floats bias = 50688 B

#define HB_WORDS 32768      // words per h buffer: 64*512

typedef __attribute__((ext_vector_type(8))) short short8x;        // 8 bf16
typedef __attribute__((ext_vector_type(4))) float f32x4;
typedef __attribute__((ext_vector_type(4))) unsigned int u32x4;

// fast activations: v_exp_f32 (=exp2) + v_rcp_f32, no IEEE division.
__device__ __forceinline__ float sigmoid_f(float v) {
    float e = __builtin_amdgcn_exp2f(v * -1.442695040888963f);
    return __builtin_amdgcn_rcpf(1.0f + e);
}
__device__ __forceinline__ float tanh_f(float v) {
    float e = __builtin_amdgcn_exp2f(v * 2.885390081777927f);
    return 1.0f - 2.0f * __builtin_amdgcn_rcpf(e + 1.0f);
}
__device__ __forceinline__ unsigned short f2bf(float f) {
    unsigned int u = __float_as_uint(f);
    return (unsigned short)((u + 0x7fffu + ((u >> 16) & 1u)) >> 16);  // RNE
}
__device__ __forceinline__ unsigned long long pack4(float4 v) {
    unsigned long long b0 = f2bf(v.x), b1 = f2bf(v.y), b2 = f2bf(v.z), b3 = f2bf(v.w);
    return b0 | (b1 << 16) | (b2 << 32) | (b3 << 48);
}
// one-instr packed f32->bf16 (RNE), lo=a, hi=b
__device__ __forceinline__ unsigned int cvtpk_bf16(float a, float b) {
    unsigned int r;
    asm("v_cvt_pk_bf16_f32 %0, %1, %2" : "=v"(r) : "v"(a), "v"(b));
    return r;
}
__device__ __forceinline__ unsigned int pklo(unsigned int a, unsigned int b) {
    return (a & 0xffffu) | (b << 16);     // two bf16 payloads -> one u32
}
__device__ __forceinline__ float bf_lo(unsigned int w) { return __uint_as_float(w << 16); }
__device__ __forceinline__ float bf_hi(unsigned int w) { return __uint_as_float(w & 0xffff0000u); }

__global__ void __launch_bounds__(256, 1) lstm_persistent(
    const float* __restrict__ x,      // [64][1024][256]
    const float* __restrict__ w_ih,   // [2048][256]
    const float* __restrict__ w_hh,   // [2048][512]
    const float* __restrict__ b_ih,   // [2048]
    const float* __restrict__ b_hh,   // [2048]
    float* __restrict__ out,          // [64][1024][512] + h_n + c_n
    unsigned int* __restrict__ h_tb)  // tagged h: [2][64][512] uint32 in ws
{
    const int tid = threadIdx.x;
    const int wg  = blockIdx.x;
    const int bg  = wg >> 3;     // 0..3
    const int hg  = wg & 7;      // 0..7

    extern __shared__ char smem[];
    unsigned short* a0 = (unsigned short*)smem;
    unsigned short* a1 = a0 + ABUF_USHORT;
    float* bias_s = (float*)(smem + BIAS_OFF);

    const int wv   = tid >> 6;          // wave 0..3
    const int lane = tid & 63;
    const int ln   = lane & 15;         // A-row supplied / batch col of D
    const int q    = lane >> 4;         // quad: k-slice of A/B, hsub of D

    // ---- one-time: weights -> VGPR/AGPR (4 tiles per wave) ----
    // A row r=ln of tile tau: gate g=ln&3, hsub=ln>>2;
    // global gate row = g*512 + hg*64 + wv*16 + hsub*4 + tau.
    short8x af0[24], af1[24], af2[24], af3[24];
    {
        const int grb = (ln & 3) * HDIM + hg * 64 + wv * 16 + (ln >> 2) * 4;
#define LOADW(AF, TAU)                                                        \
        {                                                                     \
            const int gr = grb + (TAU);                                       \
            _Pragma("unroll")                                                 \
            for (int s = 0; s < 24; ++s) {                                    \
                const float* src = (s < 8)                                    \
                    ? (w_ih + (size_t)gr * IDIM + (s * 32 + q * 8))           \
                    : (w_hh + (size_t)gr * HDIM + ((s - 8) * 32 + q * 8));    \
                float4 v0 = *(const float4*)(src);                            \
                float4 v1 = *(const float4*)(src + 4);                        \
                union { short8x v; unsigned long long u[2]; } tmp;            \
                tmp.u[0] = pack4(v0);                                         \
                tmp.u[1] = pack4(v1);                                         \
                AF[s] = tmp.v;                                                \
            }                                                                 \
        }
        LOADW(af0, 0) LOADW(af1, 1) LOADW(af2, 2) LOADW(af3, 3)
#undef LOADW
    }

    // ---- bias -> LDS. Lane-set ln<4 covers tau=ln for its (wv,q). ----
    if (ln < 4) {
        const int tau = ln;
        const int hid = hg * 64 + wv * 16 + q * 4 + tau;
        #pragma unroll
        for (int j = 0; j < 4; ++j)
            bias_s[(wv * 4 + q) * 16 + tau * 4 + j] =
                b_ih[j * HDIM + hid] + b_hh[j * HDIM + hid];
    }

    // ---- per-thread mappings ----
    const int sn  = tid >> 4;           // 0..15 (local batch, staging role)
    const int sj  = tid & 15;           // 0..15
    const int gbn = bg * 16 + sn;       // global batch for staging role
    const float* xbase = x + (size_t)gbn * TSTEPS * IDIM + sj * 16;

    // producer: lane (wv,q,ln) -> batch bg*16+ln, hiddens hg*64+wv*16+q*4 +0..3
    const size_t hb_off = (size_t)(bg * 16 + ln) * HDIM + hg * 64 + wv * 16 + q * 4;
    float c0 = 0.f, c1 = 0.f, c2 = 0.f, c3 = 0.f;
    float hf0 = 0.f, hf1 = 0.f, hf2 = 0.f, hf3 = 0.f;

    for (int t = 0; t < TSTEPS; ++t) {
        unsigned short* abuf  = (t & 1) ? a1 : a0;
        unsigned short* axp   = abuf + sn * WS + sj * 16;                   // x region
        unsigned int*   ahp32 = (unsigned int*)(abuf + sn * WS + IDIM + sj * 32);

        // ---- issue x_t loads NOW; they drain under the poll's vmcnt(0) ----
        const float* xp = xbase + (size_t)t * IDIM;
        f32x4 xv0, xv1, xv2, xv3;
        asm volatile("global_load_dwordx4 %0, %1, off"           : "=v"(xv0) : "v"(xp));
        asm volatile("global_load_dwordx4 %0, %1, off offset:16" : "=v"(xv1) : "v"(xp));
        asm volatile("global_load_dwordx4 %0, %1, off offset:32" : "=v"(xv2) : "v"(xp));
        asm volatile("global_load_dwordx4 %0, %1, off offset:48" : "=v"(xv3) : "v"(xp));

        // ---- poll tagged h_t (tag == t) with 16B system-scope loads ----
        if (t > 0) {
            const unsigned int* hp =
                h_tb + (size_t)(t & 1) * HB_WORDS + (size_t)gbn * HDIM + sj * 32;
            u32x4 hv[8];
            const unsigned int tagw = (unsigned int)t << 16;
            unsigned pend = 0xffu;
            while (pend) {
#define POLL1(U, OFF)                                                         \
                if (pend & (1u << U))                                         \
                    asm volatile("global_load_dwordx4 %0, %1, off offset:" OFF \
                                 " sc0 sc1"                                   \
                                 : "=v"(hv[U]) : "v"(hp) : "memory");
                POLL1(0, "0")  POLL1(1, "16") POLL1(2, "32") POLL1(3, "48")
                POLL1(4, "64") POLL1(5, "80") POLL1(6, "96") POLL1(7, "112")
#undef POLL1
                asm volatile("s_waitcnt vmcnt(0)" ::: "memory");
                __builtin_amdgcn_sched_barrier(0);
                unsigned np = 0;
                #pragma unroll
                for (int u = 0; u < 8; ++u) {
                    if (pend & (1u << u)) {
                        unsigned m = ((hv[u][0] ^ tagw) | (hv[u][1] ^ tagw) |
                                      (hv[u][2] ^ tagw) | (hv[u][3] ^ tagw))
                                     & 0xffff0000u;
                        if (m) np |= (1u << u);
                    }
                }
                pend = np;
            }
            // payload -> LDS h region (packed bf16 pairs)
            #pragma unroll
            for (int v = 0; v < 4; ++v) {
                u32x4 a = hv[2 * v], b = hv[2 * v + 1];
                u32x4 w4;
                w4[0] = pklo(a[0], a[1]);
                w4[1] = pklo(a[2], a[3]);
                w4[2] = pklo(b[0], b[1]);
                w4[3] = pklo(b[2], b[3]);
                *(u32x4*)(ahp32 + 4 * v) = w4;
            }
        } else {
            u32x4 z = {0u, 0u, 0u, 0u};
            #pragma unroll
            for (int v = 0; v < 4; ++v) *(u32x4*)(ahp32 + 4 * v) = z;
        }

        // ---- x is in flight; wait, fence (rule 18), pack via cvt_pk ----
        asm volatile("s_waitcnt vmcnt(0)" ::: "memory");
        __builtin_amdgcn_sched_barrier(0);
        {
            unsigned int* axp32 = (unsigned int*)axp;
            u32x4 xa, xb;
            xa[0] = cvtpk_bf16(xv0[0], xv0[1]);
            xa[1] = cvtpk_bf16(xv0[2], xv0[3]);
            xa[2] = cvtpk_bf16(xv1[0], xv1[1]);
            xa[3] = cvtpk_bf16(xv1[2], xv1[3]);
            xb[0] = cvtpk_bf16(xv2[0], xv2[1]);
            xb[1] = cvtpk_bf16(xv2[2], xv2[3]);
            xb[2] = cvtpk_bf16(xv3[0], xv3[1]);
            xb[3] = cvtpk_bf16(xv3[2], xv3[3]);
            *(u32x4*)(axp32)     = xa;
            *(u32x4*)(axp32 + 4) = xb;
        }
        __syncthreads();   // the ONLY barrier per step: a_s[t&1] staged

        // ---- MFMA: [256 x 768] x [768 x 16], wave = 4 tiles, full K ----
        const unsigned short* Bbase = abuf + (size_t)ln * WS + q * 8;
        f32x4 ac0 = {0.f, 0.f, 0.f, 0.f};
        f32x4 ac1 = {0.f, 0.f, 0.f, 0.f};
        f32x4 ac2 = {0.f, 0.f, 0.f, 0.f};
        f32x4 ac3 = {0.f, 0.f, 0.f, 0.f};
        #pragma unroll
        for (int s = 0; s < 24; ++s) {
            short8x bf = *(const short8x*)(Bbase + s * 32);
            ac0 = __builtin_amdgcn_mfma_f32_16x16x32_bf16(af0[s], bf, ac0, 0, 0, 0);
            ac1 = __builtin_amdgcn_mfma_f32_16x16x32_bf16(af1[s], bf, ac1, 0, 0, 0);
            ac2 = __builtin_amdgcn_mfma_f32_16x16x32_bf16(af2[s], bf, ac2, 0, 0, 0);
            ac3 = __builtin_amdgcn_mfma_f32_16x16x32_bf16(af3[s], bf, ac3, 0, 0, 0);
        }

        // ---- lane-local activation (reg j = gate j) + packed publish ----
        const unsigned int tagw1 = (unsigned int)(t + 1) << 16;
        const float* bsl = bias_s + (wv * 4 + q) * 16;
        u32x4 pub;
#define ACT(ACC, TAU, CREF, HREF)                                             \
        {                                                                     \
            f32x4 bs = *(const f32x4*)(bsl + (TAU) * 4);                      \
            float ig = sigmoid_f(ACC[0] + bs[0]);                             \
            float fg = sigmoid_f(ACC[1] + bs[1]);                             \
            float gt = tanh_f   (ACC[2] + bs[2]);                             \
            float og = sigmoid_f(ACC[3] + bs[3]);                             \
            CREF = fg * CREF + ig * gt;                                       \
            HREF = og * tanh_f(CREF);                                         \
            pub[TAU] = tagw1 | (cvtpk_bf16(HREF, HREF) & 0xffffu);            \
        }
        ACT(ac0, 0, c0, hf0)
        ACT(ac1, 1, c1, hf1)
        ACT(ac2, 2, c2, hf2)
        ACT(ac3, 3, c3, hf3)
#undef ACT
        {
            unsigned int* hb = h_tb + (size_t)((t + 1) & 1) * HB_WORDS + hb_off;
            asm volatile("global_store_dwordx4 %0, %1, off sc0 sc1"
                         :: "v"(hb), "v"(pub) : "memory");
        }

        // ---- out[:,t-1,:] AFTER publish, re-read from LDS; the store ack
        // drains inside the NEXT step's poll wait, not at this barrier. ----
        if (t > 0 && (sn & 7) == ((hg + t) & 7)) {
            float* op = out + ((size_t)gbn * TSTEPS + (t - 1)) * HDIM + sj * 32;
            #pragma unroll
            for (int v = 0; v < 4; ++v) {
                u32x4 w4 = *(const u32x4*)(ahp32 + 4 * v);
                f32x4 o0, o1;
                o0[0] = bf_lo(w4[0]); o0[1] = bf_hi(w4[0]);
                o0[2] = bf_lo(w4[1]); o0[3] = bf_hi(w4[1]);
                o1[0] = bf_lo(w4[2]); o1[1] = bf_hi(w4[2]);
                o1[2] = bf_lo(w4[3]); o1[3] = bf_hi(w4[3]);
                __builtin_nontemporal_store(o0, (f32x4*)(op + 8 * v));
                __builtin_nontemporal_store(o1, (f32x4*)(op + 8 * v + 4));
            }
        }
        // no trailing barrier: next-iter staging targets the OTHER a_s buffer,
        // and passing the next barrier implies all waves left this MFMA phase.
    }

    // ---- final row out[:,1023,:] + h_n, c_n (lanes hold h_T, c_T) ----
    {
        const size_t HN_OFF = (size_t)NBATCH * TSTEPS * HDIM;   // 33554432
        const size_t CN_OFF = HN_OFF + (size_t)NBATCH * HDIM;   // +32768
        const int gb   = bg * 16 + ln;
        const int hid0 = hg * 64 + wv * 16 + q * 4;
        f32x4 hv4 = {hf0, hf1, hf2, hf3};
        f32x4 cv4 = {c0, c1, c2, c3};
        *(f32x4*)(out + ((size_t)gb * TSTEPS + (TSTEPS - 1)) * HDIM + hid0) = hv4;
        *(f32x4*)(out + HN_OFF + (size_t)gb * HDIM + hid0) = hv4;
        *(f32x4*)(out + CN_OFF + (size_t)gb * HDIM + hid0) = cv4;
    }
}

extern "C" void kernel_launch(void* const* d_in, const int* in_sizes, int n_in,
                              void* d_out, int out_size, void* d_ws, size_t ws_size,
                              hipStream_t stream) {
    const float* x    = (const float*)d_in[0];
    const float* w_ih = (const float*)d_in[1];
    const float* w_hh = (const float*)d_in[2];
    const float* b_ih = (const float*)d_in[3];
    const float* b_hh = (const float*)d_in[4];
    float* out = (float*)d_out;

    // ws: [0, 256KB) tagged h double-buffer. No zeroing needed: 0xAAAA poison
    // can never equal a live tag (tags are 1..1024).
    unsigned int* h_tb = (unsigned int*)d_ws;

    (void)hipFuncSetAttribute((const void*)lstm_persistent,
                        hipFuncAttributeMaxDynamicSharedMemorySize, SMEM_BYTES);

    void* args[] = {(void*)&x, (void*)&w_ih, (void*)&w_hh, (void*)&b_ih,
                    (void*)&b_hh, (void*)&out, (void*)&h_tb};
    hipError_t err = hipLaunchCooperativeKernel((void*)lstm_persistent,
                                                dim3(32), dim3(256), args,
                                                SMEM_BYTES, stream);
    if (err != hipSuccess) {
        hipLaunchKernelGGL(lstm_persistent, dim3(32), dim3(256), SMEM_BYTES,
                           stream, x, w_ih, w_hh, b_ih, b_hh, out, h_tb);
    }
}